// Round 8
// baseline (11.727 us; speedup 1.0000x reference)
//
#include <hip/hip_runtime.h>
#include <math.h>

#define NROWS 8192
#define KP1   17
#define NWAVES (NROWS / 4)   // 4 rows per wave -> 2048 per-wave partials

// ---- Kernel A: 16 lanes per row, 4 rows per wave, NO block-level sync.
// Lane k gathers idx[k]; idx[16] is uniform per 16-lane group (broadcast).
// Group leaders (k==0) hold row sums; exp them and wave-reduce the 4 exps
// with two fixed shuffles; lane 0 writes one per-wave partial.
__global__ __launch_bounds__(512) void gather_sum_kernel(
    const float* __restrict__ data,
    const int* __restrict__ nidx,
    float* __restrict__ a_raw,
    float* __restrict__ partial)
{
    const int t   = threadIdx.x;
    const int tid = blockIdx.x * 512 + t;
    const int row = tid >> 4;
    const int k   = tid & 15;

    const int* ip = nidx + row * KP1;
    int c0  = ip[k];        // per-lane index
    int c16 = ip[16];       // uniform per 16-lane group: broadcast line

    const float* rp = data + (size_t)row * NROWS;
    float v   = rp[c0];
    float v16 = rp[c16];

    v += (k == 0) ? v16 : 0.0f;

    #pragma unroll
    for (int off = 8; off > 0; off >>= 1)
        v += __shfl_down(v, off, 16);

    float e = (k == 0) ? expf(v) : 0.0f;   // |A_raw| <= ~25: f32-safe, no max pass
    if (k == 0) a_raw[row] = v;

    // sum the 4 nonzero lanes (0,16,32,48): fixed 2-step tree, deterministic
    e += __shfl_down(e, 32, 64);
    e += __shfl_down(e, 16, 64);
    if ((t & 63) == 0) partial[tid >> 6] = e;
}

// ---- Kernel B: 32 blocks x 256 threads (round-6 winner shape). Each block
// reduces the 2048 per-wave partials (8 KB, L2-hit, fixed tree) and
// normalizes its own 256-row slice.
__global__ __launch_bounds__(256) void softmax_norm_kernel(
    const float* __restrict__ a_raw,
    const float* __restrict__ partial,
    float* __restrict__ alpha)
{
    __shared__ float red[4];
    const int t    = threadIdx.x;
    const int wave = t >> 6;
    const int lane = t & 63;
    const int row  = blockIdx.x * 256 + t;

    float e = expf(a_raw[row]);      // independent chain, issues immediately

    const float4* p4 = (const float4*)partial;   // 2048 floats = 512 float4
    float4 a = p4[t];
    float4 b = p4[t + 256];
    float s = ((a.x + a.y) + (a.z + a.w)) + ((b.x + b.y) + (b.z + b.w));
    #pragma unroll
    for (int off = 32; off > 0; off >>= 1)
        s += __shfl_down(s, off, 64);
    if (lane == 0) red[wave] = s;
    __syncthreads();
    if (t == 0) red[0] = (red[0] + red[1]) + (red[2] + red[3]);
    __syncthreads();

    alpha[row] = e * (1.0f / red[0]);
}

extern "C" void kernel_launch(void* const* d_in, const int* in_sizes, int n_in,
                              void* d_out, int out_size, void* d_ws, size_t ws_size,
                              hipStream_t stream) {
    const float* data = (const float*)d_in[0];
    const int*   nidx = (const int*)d_in[1];
    float* alpha   = (float*)d_out;            // output 0: alpha (8192)
    float* a_raw   = (float*)d_out + NROWS;    // output 1: A_raw (8192)
    float* partial = (float*)d_ws;             // 2048 floats

    gather_sum_kernel<<<(NROWS * 16) / 512, 512, 0, stream>>>(data, nidx, a_raw, partial);
    softmax_norm_kernel<<<32, 256, 0, stream>>>(a_raw, partial, alpha);
}

// Round 9
// 11.335 us; speedup vs baseline: 1.0346x; 1.0346x over previous
//
#include <hip/hip_runtime.h>
#include <math.h>

#define NROWS 8192
#define KP1   17
#define RPB_A 32    // rows per block in kernel A (512 threads / 16 lanes)

// ---- Kernel A: 16 lanes per row; also produces per-block partial exp-sums.
// 256 blocks x 512 threads. Lane k gathers idx[k]; idx[16] is wave-uniform
// per 16-lane group (broadcast line) and added at lane 0.
// Best-measured variant (round 6: 11.31 us).
__global__ __launch_bounds__(512) void gather_sum_kernel(
    const float* __restrict__ data,
    const int* __restrict__ nidx,
    float* __restrict__ a_raw,
    float* __restrict__ partial)
{
    __shared__ float lds_exp[RPB_A];

    const int t   = threadIdx.x;
    int tid = blockIdx.x * 512 + t;
    int row = tid >> 4;
    int k   = tid & 15;

    const int* ip = nidx + row * KP1;
    int c0  = ip[k];        // per-lane index
    int c16 = ip[16];       // uniform per 16-lane group: broadcast line

    const float* rp = data + (size_t)row * NROWS;
    float v   = rp[c0];
    float v16 = rp[c16];

    v += (k == 0) ? v16 : 0.0f;

    #pragma unroll
    for (int off = 8; off > 0; off >>= 1)
        v += __shfl_down(v, off, 16);

    if (k == 0) {
        a_raw[row] = v;
        lds_exp[t >> 4] = expf(v);   // no max-subtraction: |A_raw| <= ~25
    }
    __syncthreads();

    // block partial: fixed shuffle tree over 32 row-exps (deterministic)
    if (t < 32) {
        float p = lds_exp[t];
        #pragma unroll
        for (int off = 16; off > 0; off >>= 1)
            p += __shfl_down(p, off, 32);
        if (t == 0) partial[blockIdx.x] = p;
    }
}

// ---- Kernel B: 32 blocks x 256 threads. Each block reduces the 256 partials
// (1 KB, L2-hit, fixed tree) and normalizes its own 256-row slice.
__global__ __launch_bounds__(256) void softmax_norm_kernel(
    const float* __restrict__ a_raw,
    const float* __restrict__ partial,
    float* __restrict__ alpha)
{
    __shared__ float red[4];
    const int t    = threadIdx.x;
    const int wave = t >> 6;
    const int lane = t & 63;
    const int row  = blockIdx.x * 256 + t;

    float e = expf(a_raw[row]);      // start the dependent chain early

    float s = partial[t];
    #pragma unroll
    for (int off = 32; off > 0; off >>= 1)
        s += __shfl_down(s, off, 64);
    if (lane == 0) red[wave] = s;
    __syncthreads();
    if (t == 0) red[0] = (red[0] + red[1]) + (red[2] + red[3]);
    __syncthreads();

    alpha[row] = e * (1.0f / red[0]);
}

extern "C" void kernel_launch(void* const* d_in, const int* in_sizes, int n_in,
                              void* d_out, int out_size, void* d_ws, size_t ws_size,
                              hipStream_t stream) {
    const float* data = (const float*)d_in[0];
    const int*   nidx = (const int*)d_in[1];
    float* alpha   = (float*)d_out;            // output 0: alpha (8192)
    float* a_raw   = (float*)d_out + NROWS;    // output 1: A_raw (8192)
    float* partial = (float*)d_ws;             // 256 floats

    gather_sum_kernel<<<(NROWS * 16) / 512, 512, 0, stream>>>(data, nidx, a_raw, partial);
    softmax_norm_kernel<<<32, 256, 0, stream>>>(a_raw, partial, alpha);
}